// Round 10
// baseline (691.089 us; speedup 1.0000x reference)
//
#include <hip/hip_runtime.h>

#define BATCH 8192
#define NSTEP 29
#define BTILE 32
#define BT    1024         // 16 waves: 13 compute (N-tiles), 3 input-staging
#define XS    72           // x: [0,48)=tactile/out4, [48,54)=act, [54,60)=state, [60]=1
#define HS    232          // h1: [0,200)=h, [208]=1 (W2 bias col)
#define H2S   264          // h2cat: [0,200)=h2, [200,248)=inp, [248]=1
#define OS    232          // o3: [0,200)=o3, [208]=1 (FC2 bias col)

#define NFRAG 112          // per-wave frags/step: P1 36 | P2 56 | P3 8 | P4 8 | pad 4
#define WTOT  (13 * NFRAG * 512)

typedef __bf16 bf16x8 __attribute__((ext_vector_type(8)));
typedef float  f32x4  __attribute__((ext_vector_type(4)));

#define MFMA(a, b, c) __builtin_amdgcn_mfma_f32_16x16x32_bf16(a, b, c, 0, 0, 0)

__device__ __forceinline__ unsigned short f2bf(float f) {
    union { float f; unsigned u; } v; v.f = f;
    unsigned r = v.u + 0x7fffu + ((v.u >> 16) & 1u);
    return (unsigned short)(r >> 16);
}
__device__ __forceinline__ float sigf(float x) {
    return __builtin_amdgcn_rcpf(1.0f + __expf(-x));
}
__device__ __forceinline__ float tanhf_(float x) {
    return 1.0f - 2.0f * __builtin_amdgcn_rcpf(__expf(2.0f * x) + 1.0f);
}

// 4 coalesced 16B weight loads (one group), issue order pinned
__device__ __forceinline__ void load4(bf16x8 &w0, bf16x8 &w1, bf16x8 &w2, bf16x8 &w3,
                                      const unsigned short* p) {
    asm volatile("global_load_dwordx4 %0, %4, off\n\t"
                 "global_load_dwordx4 %1, %4, off offset:1024\n\t"
                 "global_load_dwordx4 %2, %4, off offset:2048\n\t"
                 "global_load_dwordx4 %3, %4, off offset:3072"
                 : "=&v"(w0), "=&v"(w1), "=&v"(w2), "=&v"(w3)
                 : "v"(p));
}

#define VM12 do { asm volatile("s_waitcnt vmcnt(12)"); \
                  __builtin_amdgcn_sched_barrier(0); } while (0)
#define BAR  do { asm volatile("s_waitcnt lgkmcnt(0)" ::: "memory"); \
                  __builtin_amdgcn_s_barrier(); } while (0)

// issue group Gabs (slots 4*(Gabs%4)), then advance stream pointer
#define ISSUE(Gabs) do { \
    const int s_ = 4 * ((Gabs) % 4); \
    load4(wq[s_], wq[s_ + 1], wq[s_ + 2], wq[s_ + 3], spp); \
    spp += 2048; \
} while (0)

// ---- prep: per-wave contiguous, consumption-ordered frag stream [13][112][512] ----
__global__ void actp_prep(const float* __restrict__ wih1, const float* __restrict__ whh1,
                          const float* __restrict__ bih1, const float* __restrict__ bhh1,
                          const float* __restrict__ wih2, const float* __restrict__ whh2,
                          const float* __restrict__ bih2, const float* __restrict__ bhh2,
                          const float* __restrict__ fc1w, const float* __restrict__ fc1b,
                          const float* __restrict__ fc2w, const float* __restrict__ fc2b,
                          unsigned short* __restrict__ ws) {
    int i = blockIdx.x * 256 + threadIdx.x;
    if (i >= WTOT) return;
    int wid = i / (NFRAG * 512);
    int r   = i % (NFRAG * 512);
    int fi  = r >> 9;
    int le  = r & 511;
    int lane = le >> 3, e = le & 7;
    int lrow = lane & 15, lgrp = lane >> 4;
    float v = 0.f;
    if (fi < 36) {                       // W1: kc=fi/4, g=fi%4; K: x[0,60)|bias@60|h1[64,288)
        int kc = fi >> 2, g = fi & 3;
        int n = wid * 16 + lrow, k = kc * 32 + lgrp * 8 + e;
        if (n < 200) {
            int o = g * 200 + n;
            if (k < 60)                   v = wih1[o * 60 + k];
            else if (k == 60)             v = bih1[o] + bhh1[o];
            else if (k >= 64 && k < 264)  v = whh1[o * 200 + (k - 64)];
        }
    } else if (fi < 92) {                // W2: K: h1[0,200)|bias@208|h2[224,424)
        int j = fi - 36; int kc = j >> 2, g = j & 3;
        int n = wid * 16 + lrow, k = kc * 32 + lgrp * 8 + e;
        if (n < 200) {
            int o = g * 200 + n;
            if (k < 200)                   v = wih2[o * 200 + k];
            else if (k == 208)             v = bih2[o] + bhh2[o];
            else if (k >= 224 && k < 424)  v = whh2[o * 200 + (k - 224)];
        }
    } else if (fi < 100) {               // FC1: fc1w natural [0,248)|bias@248
        int n = wid * 16 + lrow, k = (fi - 92) * 32 + lgrp * 8 + e;
        if (n < 200) {
            if (k < 248)       v = fc1w[n * 248 + k];
            else if (k == 248) v = fc1b[n];
        }
    } else if (fi < 107) {               // FC2: fc2w[0,200)|bias@208 ; fi>=107 pad
        int n = (wid % 3) * 16 + lrow, k = (fi - 100) * 32 + lgrp * 8 + e;
        if (wid < 3) {
            if (k < 200)       v = fc2w[n * 200 + k];
            else if (k == 208) v = fc2b[n];
        }
    }
    ws[i] = (v == 0.f) ? (unsigned short)0 : f2bf(v);
}

__global__ __launch_bounds__(BT, 4) void actp_main(
    const float* __restrict__ tact, const float* __restrict__ acts,
    const unsigned short* __restrict__ ws, float* __restrict__ out)
{
    __shared__ alignas(16) unsigned short xbuf[BTILE * XS];
    __shared__ alignas(16) unsigned short h1buf[2][BTILE * HS];
    __shared__ alignas(16) unsigned short h2cat[2][BTILE * H2S];
    __shared__ alignas(16) unsigned short o3buf[BTILE * OS];

    const int tid  = threadIdx.x;
    const int lane = tid & 63;
    const int wid  = tid >> 6;      // 0..15
    const int lrow = lane & 15;
    const int lgrp = lane >> 4;
    const int r0   = blockIdx.x * BTILE;

    const unsigned short* spbase =
        ws + (size_t)((wid < 13) ? wid : 0) * NFRAG * 512 + (lane << 3);

    // ---- prologue ----
    for (int i = tid; i < BTILE * XS;      i += BT) xbuf[i] = 0;
    for (int i = tid; i < 2 * BTILE * HS;  i += BT) h1buf[0][i] = 0;
    for (int i = tid; i < 2 * BTILE * H2S; i += BT) h2cat[0][i] = 0;
    for (int i = tid; i < BTILE * OS;      i += BT) o3buf[i] = 0;
    __syncthreads();
    if (tid < BTILE) {
        const unsigned short ONE = 0x3F80;
        xbuf[tid * XS + 60] = ONE;
        h1buf[0][tid * HS + 208] = ONE;  h1buf[1][tid * HS + 208] = ONE;
        h2cat[0][tid * H2S + 248] = ONE; h2cat[1][tid * H2S + 248] = ONE;
        o3buf[tid * OS + 208] = ONE;
    }
    if (tid < BTILE * 6) {
        int b = tid / 6, m = tid - b * 6;
        xbuf[b * XS + 54 + m] = f2bf(acts[(size_t)(r0 + b) * 6 + m]);               // state = acts[0]
        xbuf[b * XS + 48 + m] = f2bf(acts[((size_t)1 * BATCH + r0 + b) * 6 + m]);   // action step 0
    }
    for (int i = tid; i < BTILE * 48; i += BT) {
        int b = i / 48, j = i - b * 48;
        unsigned short v = f2bf(tact[(size_t)(r0 + b) * 48 + j]);                    // tact[0]
        xbuf[b * XS + j] = v;
        h2cat[0][b * H2S + 200 + j] = v;
    }
    __syncthreads();

    float c1[2][4], c2[2][4];
#pragma unroll
    for (int m = 0; m < 2; ++m)
#pragma unroll
    for (int r = 0; r < 4; ++r) { c1[m][r] = 0.f; c2[m][r] = 0.f; }

    // continuous 16-slot FIFO: prime groups 0..2 (12 frags in flight)
    bf16x8 wq[16];
    const unsigned short* spp = spbase;
    if (wid < 13) { ISSUE(0); ISSUE(1); ISSUE(2); }

    // per-lane A bases
    const unsigned short* axb  = xbuf + lrow * XS + lgrp * 8;
    const unsigned short* axb1 = xbuf + (lrow + 16) * XS + lgrp * 8;
    const unsigned short* aob  = o3buf + lrow * OS + lgrp * 8;
    const unsigned short* aob1 = o3buf + (lrow + 16) * OS + lgrp * 8;

#pragma unroll 1
    for (int idx = 0; idx < NSTEP; ++idx) {
        const int p = idx & 1;
        unsigned short* h1n = h1buf[p];
        unsigned short* h1o = h1buf[p ^ 1];
        unsigned short* h2n = h2cat[p];
        unsigned short* h2o = h2cat[p ^ 1];
        const unsigned short* h1ob  = h1o + lrow * HS + lgrp * 8;
        const unsigned short* h1ob1 = h1o + (lrow + 16) * HS + lgrp * 8;
        const unsigned short* h1nb  = h1n + lrow * HS + lgrp * 8;
        const unsigned short* h1nb1 = h1n + (lrow + 16) * HS + lgrp * 8;
        const unsigned short* h2ob  = h2o + lrow * H2S + lgrp * 8;
        const unsigned short* h2ob1 = h2o + (lrow + 16) * H2S + lgrp * 8;
        const unsigned short* h2nb  = h2n + lrow * H2S + lgrp * 8;
        const unsigned short* h2nb1 = h2n + (lrow + 16) * H2S + lgrp * 8;

        // ======== P1: LSTM1 (x | h1_old) -> h1_new ; groups 0..8 ========
        if (wid < 13) {
            f32x4 acc[4][2];
#pragma unroll
            for (int g = 0; g < 4; ++g) { acc[g][0] = {0.f,0.f,0.f,0.f}; acc[g][1] = {0.f,0.f,0.f,0.f}; }
#pragma unroll
            for (int g = 0; g < 9; ++g) {
                ISSUE(g + 3);
                const int kc = g;
                const unsigned short* a0p = (kc < 2) ? (axb + kc * 32)  : (h1ob + kc * 32 - 64);
                const unsigned short* a1p = (kc < 2) ? (axb1 + kc * 32) : (h1ob1 + kc * 32 - 64);
                bf16x8 a0 = *(const bf16x8*)a0p;
                bf16x8 a1 = *(const bf16x8*)a1p;
                VM12;
                const int s = 4 * (g % 4);
                __builtin_amdgcn_s_setprio(1);
                acc[0][0] = MFMA(a0, wq[s],     acc[0][0]); acc[0][1] = MFMA(a1, wq[s],     acc[0][1]);
                acc[1][0] = MFMA(a0, wq[s + 1], acc[1][0]); acc[1][1] = MFMA(a1, wq[s + 1], acc[1][1]);
                acc[2][0] = MFMA(a0, wq[s + 2], acc[2][0]); acc[2][1] = MFMA(a1, wq[s + 2], acc[2][1]);
                acc[3][0] = MFMA(a0, wq[s + 3], acc[3][0]); acc[3][1] = MFMA(a1, wq[s + 3], acc[3][1]);
                __builtin_amdgcn_s_setprio(0);
            }
            const int n = wid * 16 + lrow;
#pragma unroll
            for (int m = 0; m < 2; ++m)
#pragma unroll
            for (int r = 0; r < 4; ++r) {
                float c = sigf(acc[1][m][r]) * c1[m][r] + sigf(acc[0][m][r]) * tanhf_(acc[2][m][r]);
                c1[m][r] = c;
                h1n[(m * 16 + lgrp * 4 + r) * HS + n] = f2bf(sigf(acc[3][m][r]) * tanhf_(c));
            }
        }
        BAR;

        // ======== P2: LSTM2 (h1_new | h2_old) -> h2_new ; groups 9..22 ========
        if (wid < 13) {
            f32x4 acc[4][2];
#pragma unroll
            for (int g = 0; g < 4; ++g) { acc[g][0] = {0.f,0.f,0.f,0.f}; acc[g][1] = {0.f,0.f,0.f,0.f}; }
#pragma unroll
            for (int g = 9; g < 23; ++g) {
                ISSUE(g + 3);
                const int kc = g - 9;
                const unsigned short* a0p = (kc < 7) ? (h1nb + kc * 32)  : (h2ob + kc * 32 - 224);
                const unsigned short* a1p = (kc < 7) ? (h1nb1 + kc * 32) : (h2ob1 + kc * 32 - 224);
                bf16x8 a0 = *(const bf16x8*)a0p;
                bf16x8 a1 = *(const bf16x8*)a1p;
                VM12;
                const int s = 4 * (g % 4);
                __builtin_amdgcn_s_setprio(1);
                acc[0][0] = MFMA(a0, wq[s],     acc[0][0]); acc[0][1] = MFMA(a1, wq[s],     acc[0][1]);
                acc[1][0] = MFMA(a0, wq[s + 1], acc[1][0]); acc[1][1] = MFMA(a1, wq[s + 1], acc[1][1]);
                acc[2][0] = MFMA(a0, wq[s + 2], acc[2][0]); acc[2][1] = MFMA(a1, wq[s + 2], acc[2][1]);
                acc[3][0] = MFMA(a0, wq[s + 3], acc[3][0]); acc[3][1] = MFMA(a1, wq[s + 3], acc[3][1]);
                __builtin_amdgcn_s_setprio(0);
            }
            const int n = wid * 16 + lrow;
#pragma unroll
            for (int m = 0; m < 2; ++m)
#pragma unroll
            for (int r = 0; r < 4; ++r) {
                float c = sigf(acc[1][m][r]) * c2[m][r] + sigf(acc[0][m][r]) * tanhf_(acc[2][m][r]);
                c2[m][r] = c;
                if (n < 200)
                    h2n[(m * 16 + lgrp * 4 + r) * H2S + n] = f2bf(sigf(acc[3][m][r]) * tanhf_(c));
            }
        } else if (idx < NSTEP - 1) {
            const int t3 = tid - 13 * 64;    // 0..191
            {   // action for step idx+1 = acts[idx+2]
                int b = t3 / 6, m = t3 - b * 6;
                float a = __builtin_nontemporal_load(&acts[((size_t)(idx + 2) * BATCH + r0 + b) * 6 + m]);
                xbuf[b * XS + 48 + m] = f2bf(a);
            }
            if (idx < 9) {                   // ground-truth tactile for step idx+1
#pragma unroll
                for (int rr = 0; rr < 8; ++rr) {
                    int e = t3 + rr * 192;
                    int b2 = e / 48, j2 = e - b2 * 48;
                    float t = __builtin_nontemporal_load(&tact[((size_t)(idx + 1) * BATCH + r0 + b2) * 48 + j2]);
                    unsigned short v = f2bf(t);
                    xbuf[b2 * XS + j2] = v;
                    h2cat[p ^ 1][b2 * H2S + 200 + j2] = v;   // zero W2 K-cols cover the overlap
                }
            }
        }
        BAR;

        // ======== P3: FC1 (h2_new|inp|1) -> o3 ; groups 23..24 ========
        if (wid < 13) {
            f32x4 a0c = {0.f,0.f,0.f,0.f}, a1c = {0.f,0.f,0.f,0.f};
#pragma unroll
            for (int g = 23; g < 25; ++g) {
                ISSUE(g + 3);
                if (g == 24) spp -= NFRAG * 512;    // last in-stream issue was group 27
                const int kc0 = 4 * (g - 23);
                bf16x8 a00 = *(const bf16x8*)(h2nb  + (kc0 + 0) * 32);
                bf16x8 a01 = *(const bf16x8*)(h2nb1 + (kc0 + 0) * 32);
                bf16x8 a10 = *(const bf16x8*)(h2nb  + (kc0 + 1) * 32);
                bf16x8 a11 = *(const bf16x8*)(h2nb1 + (kc0 + 1) * 32);
                bf16x8 a20 = *(const bf16x8*)(h2nb  + (kc0 + 2) * 32);
                bf16x8 a21 = *(const bf16x8*)(h2nb1 + (kc0 + 2) * 32);
                bf16x8 a30 = *(const bf16x8*)(h2nb  + (kc0 + 3) * 32);
                bf16x8 a31 = *(const bf16x8*)(h2nb1 + (kc0 + 3) * 32);
                VM12;
                const int s = 4 * (g % 4);
                __builtin_amdgcn_s_setprio(1);
                a0c = MFMA(a00, wq[s],     a0c); a1c = MFMA(a01, wq[s],     a1c);
                a0c = MFMA(a10, wq[s + 1], a0c); a1c = MFMA(a11, wq[s + 1], a1c);
                a0c = MFMA(a20, wq[s + 2], a0c); a1c = MFMA(a21, wq[s + 2], a1c);
                a0c = MFMA(a30, wq[s + 3], a0c); a1c = MFMA(a31, wq[s + 3], a1c);
                __builtin_amdgcn_s_setprio(0);
            }
            const int n = wid * 16 + lrow;
#pragma unroll
            for (int r = 0; r < 4; ++r) {
                o3buf[(lgrp * 4 + r) * OS + n]      = f2bf(tanhf_(a0c[r]));
                o3buf[(16 + lgrp * 4 + r) * OS + n] = f2bf(tanhf_(a1c[r]));
            }
        }
        BAR;

        // ======== P4: FC2 (o3|1) -> out4 ; groups 25..26, dummy 27 ========
        if (wid < 13) {
            f32x4 a0c = {0.f,0.f,0.f,0.f}, a1c = {0.f,0.f,0.f,0.f};
            // group 25: kc 0..3  (issues next step's group 0)
            {
                ISSUE(28);
                bf16x8 a00 = *(const bf16x8*)(aob  + 0 * 32);
                bf16x8 a01 = *(const bf16x8*)(aob1 + 0 * 32);
                bf16x8 a10 = *(const bf16x8*)(aob  + 1 * 32);
                bf16x8 a11 = *(const bf16x8*)(aob1 + 1 * 32);
                bf16x8 a20 = *(const bf16x8*)(aob  + 2 * 32);
                bf16x8 a21 = *(const bf16x8*)(aob1 + 2 * 32);
                bf16x8 a30 = *(const bf16x8*)(aob  + 3 * 32);
                bf16x8 a31 = *(const bf16x8*)(aob1 + 3 * 32);
                VM12;
                const int s = 4 * (25 % 4);     // 4
                __builtin_amdgcn_s_setprio(1);
                a0c = MFMA(a00, wq[s],     a0c); a1c = MFMA(a01, wq[s],     a1c);
                a0c = MFMA(a10, wq[s + 1], a0c); a1c = MFMA(a11, wq[s + 1], a1c);
                a0c = MFMA(a20, wq[s + 2], a0c); a1c = MFMA(a21, wq[s + 2], a1c);
                a0c = MFMA(a30, wq[s + 3], a0c); a1c = MFMA(a31, wq[s + 3], a1c);
                __builtin_amdgcn_s_setprio(0);
            }
            // group 26: kc 4..6 (+ bias-dummy slot, unread)  (issues next step's group 1)
            {
                ISSUE(29);
                bf16x8 a00 = *(const bf16x8*)(aob  + 4 * 32);
                bf16x8 a01 = *(const bf16x8*)(aob1 + 4 * 32);
                bf16x8 a10 = *(const bf16x8*)(aob  + 5 * 32);
                bf16x8 a11 = *(const bf16x8*)(aob1 + 5 * 32);
                bf16x8 a20 = *(const bf16x8*)(aob  + 6 * 32);
                bf16x8 a21 = *(const bf16x8*)(aob1 + 6 * 32);
                VM12;
                const int s = 4 * (26 % 4);     // 8
                __builtin_amdgcn_s_setprio(1);
                a0c = MFMA(a00, wq[s],     a0c); a1c = MFMA(a01, wq[s],     a1c);
                a0c = MFMA(a10, wq[s + 1], a0c); a1c = MFMA(a11, wq[s + 1], a1c);
                a0c = MFMA(a20, wq[s + 2], a0c); a1c = MFMA(a21, wq[s + 2], a1c);
                __builtin_amdgcn_s_setprio(0);
            }
            // dummy group 27: issue + wait only (keeps vmcnt/slot invariant)
            {
                ISSUE(30);
                VM12;
            }
            if (wid < 3 && idx >= 9) {
                const int n = wid * 16 + lrow;   // 0..47
#pragma unroll
                for (int m = 0; m < 2; ++m)
#pragma unroll
                for (int r = 0; r < 4; ++r) {
                    const int row = m * 16 + lgrp * 4 + r;
                    float o4 = tanhf_(m == 0 ? a0c[r] : a1c[r]);
                    __builtin_nontemporal_store(o4, &out[((size_t)(idx - 9) * BATCH + r0 + row) * 48 + n]);
                    unsigned short v = f2bf(o4);
                    xbuf[row * XS + n] = v;                 // next-step LSTM input
                    h2cat[p ^ 1][row * H2S + 200 + n] = v;  // next-step FC1 concat input
                }
            }
        }
        BAR;
    }
}

extern "C" void kernel_launch(void* const* d_in, const int* in_sizes, int n_in,
                              void* d_out, int out_size, void* d_ws, size_t ws_size,
                              hipStream_t stream) {
    (void)in_sizes; (void)n_in; (void)out_size; (void)ws_size;
    const float* tact = (const float*)d_in[0];
    const float* acts = (const float*)d_in[1];
    const float* wih1 = (const float*)d_in[2];
    const float* whh1 = (const float*)d_in[3];
    const float* bih1 = (const float*)d_in[4];
    const float* bhh1 = (const float*)d_in[5];
    const float* wih2 = (const float*)d_in[6];
    const float* whh2 = (const float*)d_in[7];
    const float* bih2 = (const float*)d_in[8];
    const float* bhh2 = (const float*)d_in[9];
    const float* fc1w = (const float*)d_in[10];
    const float* fc1b = (const float*)d_in[11];
    const float* fc2w = (const float*)d_in[12];
    const float* fc2b = (const float*)d_in[13];
    unsigned short* ws = (unsigned short*)d_ws;
    float* outp = (float*)d_out;

    actp_prep<<<(WTOT + 255) / 256, 256, 0, stream>>>(wih1, whh1, bih1, bhh1,
                                                      wih2, whh2, bih2, bhh2,
                                                      fc1w, fc1b, fc2w, fc2b, ws);
    actp_main<<<BATCH / BTILE, BT, 0, stream>>>(tact, acts, ws, outp);
}

// Round 11
// 594.381 us; speedup vs baseline: 1.1627x; 1.1627x over previous
//
#include <hip/hip_runtime.h>

#define BATCH 8192
#define NSTEP 29
#define BTILE 32
#define BT    1024         // 16 waves: 13 compute (N-tiles), 3 input-staging
#define XS    72           // x: [0,48)=tactile/out4, [48,54)=act, [54,60)=state, [60]=1
#define HS    232          // h1: [0,200)=h, [208]=1 (W2 bias col)
#define H2S   264          // h2cat: [0,200)=h2, [200,248)=inp, [248]=1
#define OS    232          // o3: [0,200)=o3, [208]=1 (FC2 bias col)

#define NFRAG 108          // per-wave frags/step: P1 36 | P2 56 | P3 8 | P4 7+1 dummy
#define WTOT  (13 * NFRAG * 512)

typedef __bf16 bf16x8 __attribute__((ext_vector_type(8)));
typedef float  f32x4  __attribute__((ext_vector_type(4)));

#define MFMA(a, b, c) __builtin_amdgcn_mfma_f32_16x16x32_bf16(a, b, c, 0, 0, 0)

__device__ __forceinline__ unsigned short f2bf(float f) {
    union { float f; unsigned u; } v; v.f = f;
    unsigned r = v.u + 0x7fffu + ((v.u >> 16) & 1u);
    return (unsigned short)(r >> 16);
}
__device__ __forceinline__ float sigf(float x) {
    return __builtin_amdgcn_rcpf(1.0f + __expf(-x));
}
__device__ __forceinline__ float tanhf_(float x) {
    return 1.0f - 2.0f * __builtin_amdgcn_rcpf(__expf(2.0f * x) + 1.0f);
}

// 4 coalesced 16B weight loads (one group), issue order pinned
__device__ __forceinline__ void load4(bf16x8 &w0, bf16x8 &w1, bf16x8 &w2, bf16x8 &w3,
                                      const unsigned short* p) {
    asm volatile("global_load_dwordx4 %0, %4, off\n\t"
                 "global_load_dwordx4 %1, %4, off offset:1024\n\t"
                 "global_load_dwordx4 %2, %4, off offset:2048\n\t"
                 "global_load_dwordx4 %3, %4, off offset:3072"
                 : "=&v"(w0), "=&v"(w1), "=&v"(w2), "=&v"(w3)
                 : "v"(p));
}

#define VM8 do { asm volatile("s_waitcnt vmcnt(8)"); \
                 __builtin_amdgcn_sched_barrier(0); } while (0)
#define BAR do { asm volatile("s_waitcnt lgkmcnt(0)" ::: "memory"); \
                 __builtin_amdgcn_s_barrier(); } while (0)

// issue group Gabs (slots 4*(Gabs%3)), then advance stream pointer
#define ISSUE(Gabs) do { \
    const int s_ = 4 * ((Gabs) % 3); \
    load4(wq[s_], wq[s_ + 1], wq[s_ + 2], wq[s_ + 3], spp); \
    spp += 2048; \
} while (0)

// ---- prep: per-tile contiguous, consumption-ordered frag stream [13][108][512] ----
__global__ void actp_prep(const float* __restrict__ wih1, const float* __restrict__ whh1,
                          const float* __restrict__ bih1, const float* __restrict__ bhh1,
                          const float* __restrict__ wih2, const float* __restrict__ whh2,
                          const float* __restrict__ bih2, const float* __restrict__ bhh2,
                          const float* __restrict__ fc1w, const float* __restrict__ fc1b,
                          const float* __restrict__ fc2w, const float* __restrict__ fc2b,
                          unsigned short* __restrict__ ws) {
    int i = blockIdx.x * 256 + threadIdx.x;
    if (i >= WTOT) return;
    int til = i / (NFRAG * 512);
    int r   = i % (NFRAG * 512);
    int fi  = r >> 9;
    int le  = r & 511;
    int lane = le >> 3, e = le & 7;
    int lrow = lane & 15, lgrp = lane >> 4;
    float v = 0.f;
    if (fi < 36) {                       // W1: kc=fi/4, g=fi%4; K: x[0,60)|bias@60|h1[64,288)
        int kc = fi >> 2, g = fi & 3;
        int n = til * 16 + lrow, k = kc * 32 + lgrp * 8 + e;
        if (n < 200) {
            int o = g * 200 + n;
            if (k < 60)                   v = wih1[o * 60 + k];
            else if (k == 60)             v = bih1[o] + bhh1[o];
            else if (k >= 64 && k < 264)  v = whh1[o * 200 + (k - 64)];
        }
    } else if (fi < 92) {                // W2: K: h1[0,200)|bias@208|h2[224,424)
        int j = fi - 36; int kc = j >> 2, g = j & 3;
        int n = til * 16 + lrow, k = kc * 32 + lgrp * 8 + e;
        if (n < 200) {
            int o = g * 200 + n;
            if (k < 200)                   v = wih2[o * 200 + k];
            else if (k == 208)             v = bih2[o] + bhh2[o];
            else if (k >= 224 && k < 424)  v = whh2[o * 200 + (k - 224)];
        }
    } else if (fi < 100) {               // FC1: fc1w natural [0,248)|bias@248
        int n = til * 16 + lrow, k = (fi - 92) * 32 + lgrp * 8 + e;
        if (n < 200) {
            if (k < 248)       v = fc1w[n * 248 + k];
            else if (k == 248) v = fc1b[n];
        }
    } else if (fi < 107) {               // FC2: fc2w[0,200)|bias@208 ; fi==107 dummy
        int n = til * 16 + lrow, k = (fi - 100) * 32 + lgrp * 8 + e;
        if (til < 3) {
            if (k < 200)       v = fc2w[n * 200 + k];
            else if (k == 208) v = fc2b[n];
        }
    }
    ws[i] = (v == 0.f) ? (unsigned short)0 : f2bf(v);
}

__global__ __launch_bounds__(BT, 4) void actp_main(
    const float* __restrict__ tact, const float* __restrict__ acts,
    const unsigned short* __restrict__ ws, float* __restrict__ out)
{
    __shared__ alignas(16) unsigned short xbuf[BTILE * XS];
    __shared__ alignas(16) unsigned short h1buf[2][BTILE * HS];
    __shared__ alignas(16) unsigned short h2cat[2][BTILE * H2S];
    __shared__ alignas(16) unsigned short o3buf[BTILE * OS];

    const int tid  = threadIdx.x;
    const int lane = tid & 63;
    const int wid  = tid >> 6;      // 0..15
    const int lrow = lane & 15;
    const int lgrp = lane >> 4;
    const int r0   = blockIdx.x * BTILE;

    // per-block tile rotation: decorrelate concurrent blocks' weight addresses
    // (anti-hotspot for XCD L2 banks). c-state follows the wave, tile is fixed.
    int tsum = wid + (int)blockIdx.x;
    const int tile = (wid < 13) ? (tsum % 13) : 0;

    const unsigned short* spbase =
        ws + (size_t)tile * NFRAG * 512 + (lane << 3);

    // ---- prologue ----
    for (int i = tid; i < BTILE * XS;      i += BT) xbuf[i] = 0;
    for (int i = tid; i < 2 * BTILE * HS;  i += BT) h1buf[0][i] = 0;
    for (int i = tid; i < 2 * BTILE * H2S; i += BT) h2cat[0][i] = 0;
    for (int i = tid; i < BTILE * OS;      i += BT) o3buf[i] = 0;
    __syncthreads();
    if (tid < BTILE) {
        const unsigned short ONE = 0x3F80;
        xbuf[tid * XS + 60] = ONE;
        h1buf[0][tid * HS + 208] = ONE;  h1buf[1][tid * HS + 208] = ONE;
        h2cat[0][tid * H2S + 248] = ONE; h2cat[1][tid * H2S + 248] = ONE;
        o3buf[tid * OS + 208] = ONE;
    }
    if (tid < BTILE * 6) {
        int b = tid / 6, m = tid - b * 6;
        xbuf[b * XS + 54 + m] = f2bf(acts[(size_t)(r0 + b) * 6 + m]);               // state = acts[0]
        xbuf[b * XS + 48 + m] = f2bf(acts[((size_t)1 * BATCH + r0 + b) * 6 + m]);   // action step 0
    }
    for (int i = tid; i < BTILE * 48; i += BT) {
        int b = i / 48, j = i - b * 48;
        unsigned short v = f2bf(tact[(size_t)(r0 + b) * 48 + j]);                    // tact[0]
        xbuf[b * XS + j] = v;
        h2cat[0][b * H2S + 200 + j] = v;
    }
    __syncthreads();

    float c1[2][4], c2[2][4];
#pragma unroll
    for (int m = 0; m < 2; ++m)
#pragma unroll
    for (int r = 0; r < 4; ++r) { c1[m][r] = 0.f; c2[m][r] = 0.f; }

    // continuous 12-slot FIFO: prime groups 0,1 (8 frags in flight)
    bf16x8 wq[12];
    const unsigned short* spp = spbase;
    if (wid < 13) { ISSUE(0); ISSUE(1); }

    // per-lane A bases
    const unsigned short* axb  = xbuf + lrow * XS + lgrp * 8;
    const unsigned short* axb1 = xbuf + (lrow + 16) * XS + lgrp * 8;
    const unsigned short* aob  = o3buf + lrow * OS + lgrp * 8;
    const unsigned short* aob1 = o3buf + (lrow + 16) * OS + lgrp * 8;

#pragma unroll 1
    for (int idx = 0; idx < NSTEP; ++idx) {
        const int p = idx & 1;
        unsigned short* h1n = h1buf[p];
        unsigned short* h1o = h1buf[p ^ 1];
        unsigned short* h2n = h2cat[p];
        unsigned short* h2o = h2cat[p ^ 1];
        const unsigned short* h1ob  = h1o + lrow * HS + lgrp * 8;
        const unsigned short* h1ob1 = h1o + (lrow + 16) * HS + lgrp * 8;
        const unsigned short* h1nb  = h1n + lrow * HS + lgrp * 8;
        const unsigned short* h1nb1 = h1n + (lrow + 16) * HS + lgrp * 8;
        const unsigned short* h2ob  = h2o + lrow * H2S + lgrp * 8;
        const unsigned short* h2ob1 = h2o + (lrow + 16) * H2S + lgrp * 8;
        const unsigned short* h2nb  = h2n + lrow * H2S + lgrp * 8;
        const unsigned short* h2nb1 = h2n + (lrow + 16) * H2S + lgrp * 8;

        // ======== P1: LSTM1 (x | h1_old) -> h1_new ; groups 0..8 ========
        if (wid < 13) {
            f32x4 acc[4][2];
#pragma unroll
            for (int g = 0; g < 4; ++g) { acc[g][0] = {0.f,0.f,0.f,0.f}; acc[g][1] = {0.f,0.f,0.f,0.f}; }
#pragma unroll
            for (int g = 0; g < 9; ++g) {
                ISSUE(g + 2);
                const int kc = g;
                const unsigned short* a0p = (kc < 2) ? (axb + kc * 32)  : (h1ob + kc * 32 - 64);
                const unsigned short* a1p = (kc < 2) ? (axb1 + kc * 32) : (h1ob1 + kc * 32 - 64);
                bf16x8 a0 = *(const bf16x8*)a0p;
                bf16x8 a1 = *(const bf16x8*)a1p;
                VM8;
                const int s = 4 * (g % 3);
                acc[0][0] = MFMA(a0, wq[s],     acc[0][0]); acc[0][1] = MFMA(a1, wq[s],     acc[0][1]);
                acc[1][0] = MFMA(a0, wq[s + 1], acc[1][0]); acc[1][1] = MFMA(a1, wq[s + 1], acc[1][1]);
                acc[2][0] = MFMA(a0, wq[s + 2], acc[2][0]); acc[2][1] = MFMA(a1, wq[s + 2], acc[2][1]);
                acc[3][0] = MFMA(a0, wq[s + 3], acc[3][0]); acc[3][1] = MFMA(a1, wq[s + 3], acc[3][1]);
            }
            const int n = tile * 16 + lrow;
#pragma unroll
            for (int m = 0; m < 2; ++m)
#pragma unroll
            for (int r = 0; r < 4; ++r) {
                float c = sigf(acc[1][m][r]) * c1[m][r] + sigf(acc[0][m][r]) * tanhf_(acc[2][m][r]);
                c1[m][r] = c;
                h1n[(m * 16 + lgrp * 4 + r) * HS + n] = f2bf(sigf(acc[3][m][r]) * tanhf_(c));
            }
        }
        BAR;

        // ======== P2: LSTM2 (h1_new | h2_old) -> h2_new ; groups 9..22 ========
        if (wid < 13) {
            f32x4 acc[4][2];
#pragma unroll
            for (int g = 0; g < 4; ++g) { acc[g][0] = {0.f,0.f,0.f,0.f}; acc[g][1] = {0.f,0.f,0.f,0.f}; }
#pragma unroll
            for (int g = 9; g < 23; ++g) {
                ISSUE(g + 2);
                const int kc = g - 9;
                const unsigned short* a0p = (kc < 7) ? (h1nb + kc * 32)  : (h2ob + kc * 32 - 224);
                const unsigned short* a1p = (kc < 7) ? (h1nb1 + kc * 32) : (h2ob1 + kc * 32 - 224);
                bf16x8 a0 = *(const bf16x8*)a0p;
                bf16x8 a1 = *(const bf16x8*)a1p;
                VM8;
                const int s = 4 * (g % 3);
                acc[0][0] = MFMA(a0, wq[s],     acc[0][0]); acc[0][1] = MFMA(a1, wq[s],     acc[0][1]);
                acc[1][0] = MFMA(a0, wq[s + 1], acc[1][0]); acc[1][1] = MFMA(a1, wq[s + 1], acc[1][1]);
                acc[2][0] = MFMA(a0, wq[s + 2], acc[2][0]); acc[2][1] = MFMA(a1, wq[s + 2], acc[2][1]);
                acc[3][0] = MFMA(a0, wq[s + 3], acc[3][0]); acc[3][1] = MFMA(a1, wq[s + 3], acc[3][1]);
            }
            const int n = tile * 16 + lrow;
#pragma unroll
            for (int m = 0; m < 2; ++m)
#pragma unroll
            for (int r = 0; r < 4; ++r) {
                float c = sigf(acc[1][m][r]) * c2[m][r] + sigf(acc[0][m][r]) * tanhf_(acc[2][m][r]);
                c2[m][r] = c;
                if (n < 200)
                    h2n[(m * 16 + lgrp * 4 + r) * H2S + n] = f2bf(sigf(acc[3][m][r]) * tanhf_(c));
            }
        } else if (idx < NSTEP - 1) {
            const int t3 = tid - 13 * 64;    // 0..191
            {   // action for step idx+1 = acts[idx+2]
                int b = t3 / 6, m = t3 - b * 6;
                float a = __builtin_nontemporal_load(&acts[((size_t)(idx + 2) * BATCH + r0 + b) * 6 + m]);
                xbuf[b * XS + 48 + m] = f2bf(a);
            }
            if (idx < 9) {                   // ground-truth tactile for step idx+1
#pragma unroll
                for (int rr = 0; rr < 8; ++rr) {
                    int e = t3 + rr * 192;
                    int b2 = e / 48, j2 = e - b2 * 48;
                    float t = __builtin_nontemporal_load(&tact[((size_t)(idx + 1) * BATCH + r0 + b2) * 48 + j2]);
                    unsigned short v = f2bf(t);
                    xbuf[b2 * XS + j2] = v;
                    h2cat[p ^ 1][b2 * H2S + 200 + j2] = v;   // zero W2 K-cols cover the overlap
                }
            }
        }
        BAR;

        // ======== P3: FC1 (h2_new|inp|1) -> o3 ; groups 23..24 ========
        if (wid < 13) {
            f32x4 a0c = {0.f,0.f,0.f,0.f}, a1c = {0.f,0.f,0.f,0.f};
#pragma unroll
            for (int g = 23; g < 25; ++g) {
                ISSUE(g + 2);
                if (g == 24) spp -= NFRAG * 512;    // stream wrap (next issues are step+1)
                const int kc0 = 4 * (g - 23);
                bf16x8 a00 = *(const bf16x8*)(h2nb  + (kc0 + 0) * 32);
                bf16x8 a01 = *(const bf16x8*)(h2nb1 + (kc0 + 0) * 32);
                bf16x8 a10 = *(const bf16x8*)(h2nb  + (kc0 + 1) * 32);
                bf16x8 a11 = *(const bf16x8*)(h2nb1 + (kc0 + 1) * 32);
                bf16x8 a20 = *(const bf16x8*)(h2nb  + (kc0 + 2) * 32);
                bf16x8 a21 = *(const bf16x8*)(h2nb1 + (kc0 + 2) * 32);
                bf16x8 a30 = *(const bf16x8*)(h2nb  + (kc0 + 3) * 32);
                bf16x8 a31 = *(const bf16x8*)(h2nb1 + (kc0 + 3) * 32);
                VM8;
                const int s = 4 * (g % 3);
                a0c = MFMA(a00, wq[s],     a0c); a1c = MFMA(a01, wq[s],     a1c);
                a0c = MFMA(a10, wq[s + 1], a0c); a1c = MFMA(a11, wq[s + 1], a1c);
                a0c = MFMA(a20, wq[s + 2], a0c); a1c = MFMA(a21, wq[s + 2], a1c);
                a0c = MFMA(a30, wq[s + 3], a0c); a1c = MFMA(a31, wq[s + 3], a1c);
            }
            const int n = tile * 16 + lrow;
#pragma unroll
            for (int r = 0; r < 4; ++r) {
                o3buf[(lgrp * 4 + r) * OS + n]      = f2bf(tanhf_(a0c[r]));
                o3buf[(16 + lgrp * 4 + r) * OS + n] = f2bf(tanhf_(a1c[r]));
            }
        }
        BAR;

        // ======== P4: FC2 (o3|1) -> out4 ; groups 25..26 (frag 107 = dummy) ========
        if (wid < 13) {
            f32x4 a0c = {0.f,0.f,0.f,0.f}, a1c = {0.f,0.f,0.f,0.f};
            // group 25: kc 0..3
            {
                ISSUE(27);      // ≡ group 0 of next step (wrapped pointer)
                bf16x8 a00 = *(const bf16x8*)(aob  + 0 * 32);
                bf16x8 a01 = *(const bf16x8*)(aob1 + 0 * 32);
                bf16x8 a10 = *(const bf16x8*)(aob  + 1 * 32);
                bf16x8 a11 = *(const bf16x8*)(aob1 + 1 * 32);
                bf16x8 a20 = *(const bf16x8*)(aob  + 2 * 32);
                bf16x8 a21 = *(const bf16x8*)(aob1 + 2 * 32);
                bf16x8 a30 = *(const bf16x8*)(aob  + 3 * 32);
                bf16x8 a31 = *(const bf16x8*)(aob1 + 3 * 32);
                VM8;
                const int s = 4 * (25 % 3);     // 4
                a0c = MFMA(a00, wq[s],     a0c); a1c = MFMA(a01, wq[s],     a1c);
                a0c = MFMA(a10, wq[s + 1], a0c); a1c = MFMA(a11, wq[s + 1], a1c);
                a0c = MFMA(a20, wq[s + 2], a0c); a1c = MFMA(a21, wq[s + 2], a1c);
                a0c = MFMA(a30, wq[s + 3], a0c); a1c = MFMA(a31, wq[s + 3], a1c);
            }
            // group 26: kc 4..6 (+ dummy slot, unread)
            {
                ISSUE(28);      // ≡ group 1 of next step
                bf16x8 a00 = *(const bf16x8*)(aob  + 4 * 32);
                bf16x8 a01 = *(const bf16x8*)(aob1 + 4 * 32);
                bf16x8 a10 = *(const bf16x8*)(aob  + 5 * 32);
                bf16x8 a11 = *(const bf16x8*)(aob1 + 5 * 32);
                bf16x8 a20 = *(const bf16x8*)(aob  + 6 * 32);
                bf16x8 a21 = *(const bf16x8*)(aob1 + 6 * 32);
                VM8;
                const int s = 4 * (26 % 3);     // 8
                a0c = MFMA(a00, wq[s],     a0c); a1c = MFMA(a01, wq[s],     a1c);
                a0c = MFMA(a10, wq[s + 1], a0c); a1c = MFMA(a11, wq[s + 1], a1c);
                a0c = MFMA(a20, wq[s + 2], a0c); a1c = MFMA(a21, wq[s + 2], a1c);
            }
            if (tile < 3 && idx >= 9) {
                const int n = tile * 16 + lrow;   // 0..47
#pragma unroll
                for (int m = 0; m < 2; ++m)
#pragma unroll
                for (int r = 0; r < 4; ++r) {
                    const int row = m * 16 + lgrp * 4 + r;
                    float o4 = tanhf_(m == 0 ? a0c[r] : a1c[r]);
                    __builtin_nontemporal_store(o4, &out[((size_t)(idx - 9) * BATCH + r0 + row) * 48 + n]);
                    unsigned short v = f2bf(o4);
                    xbuf[row * XS + n] = v;                 // next-step LSTM input
                    h2cat[p ^ 1][row * H2S + 200 + n] = v;  // next-step FC1 concat input
                }
            }
        }
        BAR;
    }
}

extern "C" void kernel_launch(void* const* d_in, const int* in_sizes, int n_in,
                              void* d_out, int out_size, void* d_ws, size_t ws_size,
                              hipStream_t stream) {
    (void)in_sizes; (void)n_in; (void)out_size; (void)ws_size;
    const float* tact = (const float*)d_in[0];
    const float* acts = (const float*)d_in[1];
    const float* wih1 = (const float*)d_in[2];
    const float* whh1 = (const float*)d_in[3];
    const float* bih1 = (const float*)d_in[4];
    const float* bhh1 = (const float*)d_in[5];
    const float* wih2 = (const float*)d_in[6];
    const float* whh2 = (const float*)d_in[7];
    const float* bih2 = (const float*)d_in[8];
    const float* bhh2 = (const float*)d_in[9];
    const float* fc1w = (const float*)d_in[10];
    const float* fc1b = (const float*)d_in[11];
    const float* fc2w = (const float*)d_in[12];
    const float* fc2b = (const float*)d_in[13];
    unsigned short* ws = (unsigned short*)d_ws;
    float* outp = (float*)d_out;

    actp_prep<<<(WTOT + 255) / 256, 256, 0, stream>>>(wih1, whh1, bih1, bhh1,
                                                      wih2, whh2, bih2, bhh2,
                                                      fc1w, fc1b, fc2w, fc2b, ws);
    actp_main<<<BATCH / BTILE, BT, 0, stream>>>(tact, acts, ws, outp);
}

// Round 13
// 584.553 us; speedup vs baseline: 1.1823x; 1.0168x over previous
//
#include <hip/hip_runtime.h>

#define BATCH 8192
#define NSTEP 29
#define BTILE 32
#define BT    1024         // 16 waves: 13 compute (N-tiles), 3 input-staging
#define XS    72           // x: [0,48)=tactile/out4, [48,54)=act, [54,60)=state, [60]=1
#define HS    232          // h1: [0,200)=h, [208]=1 (W2 bias col)
#define H2S   264          // h2cat: [0,200)=h2, [200,248)=inp, [248]=1
#define OS    232          // o3: [0,200)=o3, [208]=1 (FC2 bias col)

#define NFRAG 108          // per-wave frags/step: P1 36 | P2 56 | P3 8 | P4 7+1 dummy
#define WTOT  (13 * NFRAG * 512)

typedef __bf16 bf16x8 __attribute__((ext_vector_type(8)));
typedef float  f32x4  __attribute__((ext_vector_type(4)));

#define MFMA(a, b, c) __builtin_amdgcn_mfma_f32_16x16x32_bf16(a, b, c, 0, 0, 0)

__device__ __forceinline__ unsigned short f2bf(float f) {
    union { float f; unsigned u; } v; v.f = f;
    unsigned r = v.u + 0x7fffu + ((v.u >> 16) & 1u);
    return (unsigned short)(r >> 16);
}
__device__ __forceinline__ float sigf(float x) {
    return __builtin_amdgcn_rcpf(1.0f + __expf(-x));
}
__device__ __forceinline__ float tanhf_(float x) {
    return 1.0f - 2.0f * __builtin_amdgcn_rcpf(__expf(2.0f * x) + 1.0f);
}

// 4 coalesced 16B weight loads (one group), issue order pinned
__device__ __forceinline__ void load4(bf16x8 &w0, bf16x8 &w1, bf16x8 &w2, bf16x8 &w3,
                                      const unsigned short* p) {
    asm volatile("global_load_dwordx4 %0, %4, off\n\t"
                 "global_load_dwordx4 %1, %4, off offset:1024\n\t"
                 "global_load_dwordx4 %2, %4, off offset:2048\n\t"
                 "global_load_dwordx4 %3, %4, off offset:3072"
                 : "=&v"(w0), "=&v"(w1), "=&v"(w2), "=&v"(w3)
                 : "v"(p));
}

#define VM8 do { asm volatile("s_waitcnt vmcnt(8)"); \
                 __builtin_amdgcn_sched_barrier(0); } while (0)
#define BAR do { asm volatile("s_waitcnt lgkmcnt(0)" ::: "memory"); \
                 __builtin_amdgcn_s_barrier(); } while (0)

// issue group Gabs (slots 4*(Gabs%3)), then advance stream pointer
#define ISSUE(Gabs) do { \
    const int s_ = 4 * ((Gabs) % 3); \
    load4(wq[s_], wq[s_ + 1], wq[s_ + 2], wq[s_ + 3], spp); \
    spp += 2048; \
} while (0)

// ---- prep: per-tile contiguous, consumption-ordered frag stream [13][108][512] ----
__global__ void actp_prep(const float* __restrict__ wih1, const float* __restrict__ whh1,
                          const float* __restrict__ bih1, const float* __restrict__ bhh1,
                          const float* __restrict__ wih2, const float* __restrict__ whh2,
                          const float* __restrict__ bih2, const float* __restrict__ bhh2,
                          const float* __restrict__ fc1w, const float* __restrict__ fc1b,
                          const float* __restrict__ fc2w, const float* __restrict__ fc2b,
                          unsigned short* __restrict__ ws) {
    int i = blockIdx.x * 256 + threadIdx.x;
    if (i >= WTOT) return;
    int til = i / (NFRAG * 512);
    int r   = i % (NFRAG * 512);
    int fi  = r >> 9;
    int le  = r & 511;
    int lane = le >> 3, e = le & 7;
    int lrow = lane & 15, lgrp = lane >> 4;
    float v = 0.f;
    if (fi < 36) {                       // W1: kc=fi/4, g=fi%4; K: x[0,60)|bias@60|h1[64,288)
        int kc = fi >> 2, g = fi & 3;
        int n = til * 16 + lrow, k = kc * 32 + lgrp * 8 + e;
        if (n < 200) {
            int o = g * 200 + n;
            if (k < 60)                   v = wih1[o * 60 + k];
            else if (k == 60)             v = bih1[o] + bhh1[o];
            else if (k >= 64 && k < 264)  v = whh1[o * 200 + (k - 64)];
        }
    } else if (fi < 92) {                // W2: K: h1[0,200)|bias@208|h2[224,424)
        int j = fi - 36; int kc = j >> 2, g = j & 3;
        int n = til * 16 + lrow, k = kc * 32 + lgrp * 8 + e;
        if (n < 200) {
            int o = g * 200 + n;
            if (k < 200)                   v = wih2[o * 200 + k];
            else if (k == 208)             v = bih2[o] + bhh2[o];
            else if (k >= 224 && k < 424)  v = whh2[o * 200 + (k - 224)];
        }
    } else if (fi < 100) {               // FC1: fc1w natural [0,248)|bias@248
        int n = til * 16 + lrow, k = (fi - 92) * 32 + lgrp * 8 + e;
        if (n < 200) {
            if (k < 248)       v = fc1w[n * 248 + k];
            else if (k == 248) v = fc1b[n];
        }
    } else if (fi < 107) {               // FC2: fc2w[0,200)|bias@208 ; fi==107 dummy
        int n = til * 16 + lrow, k = (fi - 100) * 32 + lgrp * 8 + e;
        if (til < 3) {
            if (k < 200)       v = fc2w[n * 200 + k];
            else if (k == 208) v = fc2b[n];
        }
    }
    ws[i] = (v == 0.f) ? (unsigned short)0 : f2bf(v);
}

__global__ __launch_bounds__(BT, 4) void actp_main(
    const float* __restrict__ tact, const float* __restrict__ acts,
    const unsigned short* __restrict__ ws, float* __restrict__ out)
{
    __shared__ alignas(16) unsigned short xbuf[BTILE * XS];
    __shared__ alignas(16) unsigned short h1buf[2][BTILE * HS];
    __shared__ alignas(16) unsigned short h2cat[2][BTILE * H2S];
    __shared__ alignas(16) unsigned short o3buf[BTILE * OS];

    const int tid  = threadIdx.x;
    const int lane = tid & 63;
    const int wid  = tid >> 6;      // 0..15
    const int lrow = lane & 15;
    const int lgrp = lane >> 4;
    const int r0   = blockIdx.x * BTILE;

    // per-block tile rotation: decorrelates concurrent blocks' weight addresses
    // (keeps HBM FETCH low; time-neutral per R11 A/B)
    int tsum = wid + (int)blockIdx.x;
    const int tile = (wid < 13) ? (tsum % 13) : 0;

    const unsigned short* spbase =
        ws + (size_t)tile * NFRAG * 512 + (lane << 3);

    // ---- prologue ----
    for (int i = tid; i < BTILE * XS;      i += BT) xbuf[i] = 0;
    for (int i = tid; i < 2 * BTILE * HS;  i += BT) h1buf[0][i] = 0;
    for (int i = tid; i < 2 * BTILE * H2S; i += BT) h2cat[0][i] = 0;
    for (int i = tid; i < BTILE * OS;      i += BT) o3buf[i] = 0;
    __syncthreads();
    if (tid < BTILE) {
        const unsigned short ONE = 0x3F80;
        xbuf[tid * XS + 60] = ONE;
        h1buf[0][tid * HS + 208] = ONE;  h1buf[1][tid * HS + 208] = ONE;
        h2cat[0][tid * H2S + 248] = ONE; h2cat[1][tid * H2S + 248] = ONE;
        o3buf[tid * OS + 208] = ONE;
    }
    if (tid < BTILE * 6) {
        int b = tid / 6, m = tid - b * 6;
        xbuf[b * XS + 54 + m] = f2bf(acts[(size_t)(r0 + b) * 6 + m]);               // state = acts[0]
        xbuf[b * XS + 48 + m] = f2bf(acts[((size_t)1 * BATCH + r0 + b) * 6 + m]);   // action step 0
    }
    for (int i = tid; i < BTILE * 48; i += BT) {
        int b = i / 48, j = i - b * 48;
        unsigned short v = f2bf(tact[(size_t)(r0 + b) * 48 + j]);                    // tact[0]
        xbuf[b * XS + j] = v;
        h2cat[0][b * H2S + 200 + j] = v;
    }
    __syncthreads();

    float c1[2][4], c2[2][4];
#pragma unroll
    for (int m = 0; m < 2; ++m)
#pragma unroll
    for (int r = 0; r < 4; ++r) { c1[m][r] = 0.f; c2[m][r] = 0.f; }

    // continuous 12-slot FIFO: prime groups 0,1 (8 frags in flight)
    bf16x8 wq[12];
    const unsigned short* spp = spbase;
    if (wid < 13) { ISSUE(0); ISSUE(1); }

    // per-lane A bases
    const unsigned short* axb  = xbuf + lrow * XS + lgrp * 8;
    const unsigned short* axb1 = xbuf + (lrow + 16) * XS + lgrp * 8;
    const unsigned short* aob  = o3buf + lrow * OS + lgrp * 8;
    const unsigned short* aob1 = o3buf + (lrow + 16) * OS + lgrp * 8;

#pragma unroll 1
    for (int idx = 0; idx < NSTEP; ++idx) {
        const int p = idx & 1;
        unsigned short* h1n = h1buf[p];
        unsigned short* h1o = h1buf[p ^ 1];
        unsigned short* h2n = h2cat[p];
        unsigned short* h2o = h2cat[p ^ 1];
        const unsigned short* h1ob  = h1o + lrow * HS + lgrp * 8;
        const unsigned short* h1ob1 = h1o + (lrow + 16) * HS + lgrp * 8;
        const unsigned short* h1nb  = h1n + lrow * HS + lgrp * 8;
        const unsigned short* h1nb1 = h1n + (lrow + 16) * HS + lgrp * 8;
        const unsigned short* h2ob  = h2o + lrow * H2S + lgrp * 8;
        const unsigned short* h2ob1 = h2o + (lrow + 16) * H2S + lgrp * 8;
        const unsigned short* h2nb  = h2n + lrow * H2S + lgrp * 8;
        const unsigned short* h2nb1 = h2n + (lrow + 16) * H2S + lgrp * 8;

        // ======== P1: LSTM1 (x | h1_old) -> h1_new ; groups 0..8 ========
        if (wid < 13) {
            f32x4 acc[4][2];
#pragma unroll
            for (int g = 0; g < 4; ++g) { acc[g][0] = {0.f,0.f,0.f,0.f}; acc[g][1] = {0.f,0.f,0.f,0.f}; }
#pragma unroll
            for (int g = 0; g < 9; ++g) {
                ISSUE(g + 2);
                const int kc = g;
                const unsigned short* a0p = (kc < 2) ? (axb + kc * 32)  : (h1ob + kc * 32 - 64);
                const unsigned short* a1p = (kc < 2) ? (axb1 + kc * 32) : (h1ob1 + kc * 32 - 64);
                bf16x8 a0 = *(const bf16x8*)a0p;
                bf16x8 a1 = *(const bf16x8*)a1p;
                VM8;
                const int s = 4 * (g % 3);
                acc[0][0] = MFMA(a0, wq[s],     acc[0][0]); acc[0][1] = MFMA(a1, wq[s],     acc[0][1]);
                acc[1][0] = MFMA(a0, wq[s + 1], acc[1][0]); acc[1][1] = MFMA(a1, wq[s + 1], acc[1][1]);
                acc[2][0] = MFMA(a0, wq[s + 2], acc[2][0]); acc[2][1] = MFMA(a1, wq[s + 2], acc[2][1]);
                acc[3][0] = MFMA(a0, wq[s + 3], acc[3][0]); acc[3][1] = MFMA(a1, wq[s + 3], acc[3][1]);
            }
            const int n = tile * 16 + lrow;
#pragma unroll
            for (int m = 0; m < 2; ++m)
#pragma unroll
            for (int r = 0; r < 4; ++r) {
                float c = sigf(acc[1][m][r]) * c1[m][r] + sigf(acc[0][m][r]) * tanhf_(acc[2][m][r]);
                c1[m][r] = c;
                h1n[(m * 16 + lgrp * 4 + r) * HS + n] = f2bf(sigf(acc[3][m][r]) * tanhf_(c));
            }
        }
        BAR;

        // ======== P2: LSTM2 (h1_new | h2_old) -> h2_new ; groups 9..22 ========
        if (wid < 13) {
            f32x4 acc[4][2];
#pragma unroll
            for (int g = 0; g < 4; ++g) { acc[g][0] = {0.f,0.f,0.f,0.f}; acc[g][1] = {0.f,0.f,0.f,0.f}; }
#pragma unroll
            for (int g = 9; g < 23; ++g) {
                ISSUE(g + 2);
                const int kc = g - 9;
                const unsigned short* a0p = (kc < 7) ? (h1nb + kc * 32)  : (h2ob + kc * 32 - 224);
                const unsigned short* a1p = (kc < 7) ? (h1nb1 + kc * 32) : (h2ob1 + kc * 32 - 224);
                bf16x8 a0 = *(const bf16x8*)a0p;
                bf16x8 a1 = *(const bf16x8*)a1p;
                VM8;
                const int s = 4 * (g % 3);
                acc[0][0] = MFMA(a0, wq[s],     acc[0][0]); acc[0][1] = MFMA(a1, wq[s],     acc[0][1]);
                acc[1][0] = MFMA(a0, wq[s + 1], acc[1][0]); acc[1][1] = MFMA(a1, wq[s + 1], acc[1][1]);
                acc[2][0] = MFMA(a0, wq[s + 2], acc[2][0]); acc[2][1] = MFMA(a1, wq[s + 2], acc[2][1]);
                acc[3][0] = MFMA(a0, wq[s + 3], acc[3][0]); acc[3][1] = MFMA(a1, wq[s + 3], acc[3][1]);
            }
            const int n = tile * 16 + lrow;
#pragma unroll
            for (int m = 0; m < 2; ++m)
#pragma unroll
            for (int r = 0; r < 4; ++r) {
                float c = sigf(acc[1][m][r]) * c2[m][r] + sigf(acc[0][m][r]) * tanhf_(acc[2][m][r]);
                c2[m][r] = c;
                if (n < 200)
                    h2n[(m * 16 + lgrp * 4 + r) * H2S + n] = f2bf(sigf(acc[3][m][r]) * tanhf_(c));
            }
        } else if (idx < NSTEP - 1) {
            const int t3 = tid - 13 * 64;    // 0..191
            {   // action for step idx+1 = acts[idx+2]
                int b = t3 / 6, m = t3 - b * 6;
                float a = __builtin_nontemporal_load(&acts[((size_t)(idx + 2) * BATCH + r0 + b) * 6 + m]);
                xbuf[b * XS + 48 + m] = f2bf(a);
            }
            if (idx < 9) {                   // ground-truth tactile for step idx+1
#pragma unroll
                for (int rr = 0; rr < 8; ++rr) {
                    int e = t3 + rr * 192;
                    int b2 = e / 48, j2 = e - b2 * 48;
                    float t = __builtin_nontemporal_load(&tact[((size_t)(idx + 1) * BATCH + r0 + b2) * 48 + j2]);
                    unsigned short v = f2bf(t);
                    xbuf[b2 * XS + j2] = v;
                    h2cat[p ^ 1][b2 * H2S + 200 + j2] = v;   // zero W2 K-cols cover the overlap
                }
            }
        }
        BAR;

        // ======== P3: FC1 (h2_new|inp|1) -> o3 ; groups 23..24 ========
        if (wid < 13) {
            f32x4 a0c = {0.f,0.f,0.f,0.f}, a1c = {0.f,0.f,0.f,0.f};
#pragma unroll
            for (int g = 23; g < 25; ++g) {
                ISSUE(g + 2);
                if (g == 24) spp -= NFRAG * 512;    // stream wrap (next issues are step+1)
                const int kc0 = 4 * (g - 23);
                bf16x8 a00 = *(const bf16x8*)(h2nb  + (kc0 + 0) * 32);
                bf16x8 a01 = *(const bf16x8*)(h2nb1 + (kc0 + 0) * 32);
                bf16x8 a10 = *(const bf16x8*)(h2nb  + (kc0 + 1) * 32);
                bf16x8 a11 = *(const bf16x8*)(h2nb1 + (kc0 + 1) * 32);
                bf16x8 a20 = *(const bf16x8*)(h2nb  + (kc0 + 2) * 32);
                bf16x8 a21 = *(const bf16x8*)(h2nb1 + (kc0 + 2) * 32);
                bf16x8 a30 = *(const bf16x8*)(h2nb  + (kc0 + 3) * 32);
                bf16x8 a31 = *(const bf16x8*)(h2nb1 + (kc0 + 3) * 32);
                VM8;
                const int s = 4 * (g % 3);
                a0c = MFMA(a00, wq[s],     a0c); a1c = MFMA(a01, wq[s],     a1c);
                a0c = MFMA(a10, wq[s + 1], a0c); a1c = MFMA(a11, wq[s + 1], a1c);
                a0c = MFMA(a20, wq[s + 2], a0c); a1c = MFMA(a21, wq[s + 2], a1c);
                a0c = MFMA(a30, wq[s + 3], a0c); a1c = MFMA(a31, wq[s + 3], a1c);
            }
            const int n = tile * 16 + lrow;
#pragma unroll
            for (int r = 0; r < 4; ++r) {
                o3buf[(lgrp * 4 + r) * OS + n]      = f2bf(tanhf_(a0c[r]));
                o3buf[(16 + lgrp * 4 + r) * OS + n] = f2bf(tanhf_(a1c[r]));
            }
        }
        BAR;

        // ======== P4: FC2 (o3|1) -> out4 ; groups 25..26 (frag 107 = dummy) ========
        if (wid < 13) {
            f32x4 a0c = {0.f,0.f,0.f,0.f}, a1c = {0.f,0.f,0.f,0.f};
            // group 25: kc 0..3
            {
                ISSUE(27);      // ≡ group 0 of next step (wrapped pointer)
                bf16x8 a00 = *(const bf16x8*)(aob  + 0 * 32);
                bf16x8 a01 = *(const bf16x8*)(aob1 + 0 * 32);
                bf16x8 a10 = *(const bf16x8*)(aob  + 1 * 32);
                bf16x8 a11 = *(const bf16x8*)(aob1 + 1 * 32);
                bf16x8 a20 = *(const bf16x8*)(aob  + 2 * 32);
                bf16x8 a21 = *(const bf16x8*)(aob1 + 2 * 32);
                bf16x8 a30 = *(const bf16x8*)(aob  + 3 * 32);
                bf16x8 a31 = *(const bf16x8*)(aob1 + 3 * 32);
                VM8;
                const int s = 4 * (25 % 3);     // 4
                a0c = MFMA(a00, wq[s],     a0c); a1c = MFMA(a01, wq[s],     a1c);
                a0c = MFMA(a10, wq[s + 1], a0c); a1c = MFMA(a11, wq[s + 1], a1c);
                a0c = MFMA(a20, wq[s + 2], a0c); a1c = MFMA(a21, wq[s + 2], a1c);
                a0c = MFMA(a30, wq[s + 3], a0c); a1c = MFMA(a31, wq[s + 3], a1c);
            }
            // group 26: kc 4..6 (+ dummy slot, unread)
            {
                ISSUE(28);      // ≡ group 1 of next step
                bf16x8 a00 = *(const bf16x8*)(aob  + 4 * 32);
                bf16x8 a01 = *(const bf16x8*)(aob1 + 4 * 32);
                bf16x8 a10 = *(const bf16x8*)(aob  + 5 * 32);
                bf16x8 a11 = *(const bf16x8*)(aob1 + 5 * 32);
                bf16x8 a20 = *(const bf16x8*)(aob  + 6 * 32);
                bf16x8 a21 = *(const bf16x8*)(aob1 + 6 * 32);
                VM8;
                const int s = 4 * (26 % 3);     // 8
                a0c = MFMA(a00, wq[s],     a0c); a1c = MFMA(a01, wq[s],     a1c);
                a0c = MFMA(a10, wq[s + 1], a0c); a1c = MFMA(a11, wq[s + 1], a1c);
                a0c = MFMA(a20, wq[s + 2], a0c); a1c = MFMA(a21, wq[s + 2], a1c);
            }
            if (tile < 3 && idx >= 9) {
                const int n = tile * 16 + lrow;   // 0..47
#pragma unroll
                for (int m = 0; m < 2; ++m)
#pragma unroll
                for (int r = 0; r < 4; ++r) {
                    const int row = m * 16 + lgrp * 4 + r;
                    float o4 = tanhf_(m == 0 ? a0c[r] : a1c[r]);
                    __builtin_nontemporal_store(o4, &out[((size_t)(idx - 9) * BATCH + r0 + row) * 48 + n]);
                    unsigned short v = f2bf(o4);
                    xbuf[row * XS + n] = v;                 // next-step LSTM input
                    h2cat[p ^ 1][row * H2S + 200 + n] = v;  // next-step FC1 concat input
                }
            }
        }
        BAR;
    }
}

extern "C" void kernel_launch(void* const* d_in, const int* in_sizes, int n_in,
                              void* d_out, int out_size, void* d_ws, size_t ws_size,
                              hipStream_t stream) {
    (void)in_sizes; (void)n_in; (void)out_size; (void)ws_size;
    const float* tact = (const float*)d_in[0];
    const float* acts = (const float*)d_in[1];
    const float* wih1 = (const float*)d_in[2];
    const float* whh1 = (const float*)d_in[3];
    const float* bih1 = (const float*)d_in[4];
    const float* bhh1 = (const float*)d_in[5];
    const float* wih2 = (const float*)d_in[6];
    const float* whh2 = (const float*)d_in[7];
    const float* bih2 = (const float*)d_in[8];
    const float* bhh2 = (const float*)d_in[9];
    const float* fc1w = (const float*)d_in[10];
    const float* fc1b = (const float*)d_in[11];
    const float* fc2w = (const float*)d_in[12];
    const float* fc2b = (const float*)d_in[13];
    unsigned short* ws = (unsigned short*)d_ws;
    float* outp = (float*)d_out;

    actp_prep<<<(WTOT + 255) / 256, 256, 0, stream>>>(wih1, whh1, bih1, bhh1,
                                                      wih2, whh2, bih2, bhh2,
                                                      fc1w, fc1b, fc2w, fc2b, ws);
    actp_main<<<BATCH / BTILE, BT, 0, stream>>>(tact, acts, ws, outp);
}